// Round 15
// baseline (275.781 us; speedup 1.0000x reference)
//
#include <hip/hip_runtime.h>
#include <hip/hip_bf16.h>
#include <math.h>

#define H1 100
#define H2 16
#define FDIM 256
#define NPAD 112   // H1 padded to 7*16
#define BINCH 4096 // edges per binning workgroup

typedef __attribute__((ext_vector_type(8))) short bf16x8;
typedef __attribute__((ext_vector_type(4))) float f32x4;
typedef float f32x4a __attribute__((ext_vector_type(4), aligned(4)));  // 4B-aligned vec load

// ---- bf16 pack/unpack helpers ----
__device__ __forceinline__ float bf_lo(unsigned u) { return __uint_as_float(u << 16); }
__device__ __forceinline__ float bf_hi(unsigned u) { return __uint_as_float(u & 0xffff0000u); }
__device__ __forceinline__ unsigned f2bf_bits(float f) {
  unsigned x = __float_as_uint(f);
  return (x + 0x7fffu + ((x >> 16) & 1u)) >> 16;   // round-nearest-even
}
// HW packed convert: v_cvt_pk_bf16_f32 (1 instr)
__device__ __forceinline__ unsigned pack_bf16(float a, float b) {
  __hip_bfloat162 h = __float22bfloat162_rn(make_float2(a, b));
  unsigned u;
  __builtin_memcpy(&u, &h, 4);
  return u;
}
// (u-v)^2 for a packed bf16 pair -> packed bf16 pair
__device__ __forceinline__ unsigned sqd_pair(unsigned u, unsigned v) {
  float d0 = bf_lo(u) - bf_lo(v);
  float d1 = bf_hi(u) - bf_hi(v);
  return pack_bf16(d0 * d0, d1 * d1);
}

// ============ CSR build via bucket binning ==========
__global__ __launch_bounds__(256)
void k_bincnt(const int* __restrict__ dst, int* __restrict__ bucket_cnt,
              int E, int shift) {
  __shared__ int lcnt[512];
  int t = threadIdx.x;
  for (int i = t; i < 512; i += 256) lcnt[i] = 0;
  __syncthreads();
  int base = blockIdx.x * BINCH;
#pragma unroll
  for (int i = 0; i < 16; i++) {
    int e = base + t + i * 256;
    if (e < E) atomicAdd(&lcnt[dst[e] >> shift], 1);
  }
  __syncthreads();
  for (int b = t; b < 512; b += 256) {
    int c = lcnt[b];
    if (c > 0) atomicAdd(&bucket_cnt[b], c);
  }
}

__global__ void k_bscan(const int* __restrict__ bucket_cnt, int* __restrict__ bucket_base,
                        int* __restrict__ bucket_fill, int nbuc, int E) {
  __shared__ int s[512];
  int tid = threadIdx.x;
  int v = (tid < nbuc) ? bucket_cnt[tid] : 0;
  s[tid] = v;
  __syncthreads();
  for (int off = 1; off < 512; off <<= 1) {
    int tt = (tid >= off) ? s[tid - off] : 0;
    __syncthreads();
    s[tid] += tt;
    __syncthreads();
  }
  if (tid < nbuc) { int ex = s[tid] - v; bucket_base[tid] = ex; bucket_fill[tid] = ex; }
  if (tid == 0) bucket_base[nbuc] = E;
}

// pass 3: write (dst,src) int2 pairs binned by bucket (single 8B store/edge)
__global__ __launch_bounds__(256)
void k_binwrite(const int* __restrict__ src, const int* __restrict__ dst,
                int* __restrict__ bucket_fill, int2* __restrict__ tpair,
                int E, int shift) {
  __shared__ int lcnt[512];
  __shared__ int loff[512];
  int t = threadIdx.x;
  for (int i = t; i < 512; i += 256) lcnt[i] = 0;
  __syncthreads();
  int base = blockIdx.x * BINCH;
  int d[16], s_[16];
#pragma unroll
  for (int i = 0; i < 16; i++) {
    int e = base + t + i * 256;
    if (e < E) {
      d[i] = dst[e]; s_[i] = src[e];
      atomicAdd(&lcnt[d[i] >> shift], 1);
    } else d[i] = -1;
  }
  __syncthreads();
  for (int b = t; b < 512; b += 256) {
    int c = lcnt[b];
    loff[b] = (c > 0) ? atomicAdd(&bucket_fill[b], c) : 0;
  }
  __syncthreads();
#pragma unroll
  for (int i = 0; i < 16; i++) {
    if (d[i] >= 0) {
      int p = atomicAdd(&loff[d[i] >> shift], 1);
      tpair[p] = make_int2(d[i], s_[i]);
    }
  }
}

// pass 4: per-bucket degree histogram + IN-LDS exclusive scan -> row_ptr, dinv
__global__ __launch_bounds__(256)
void k_deg2s(const int2* __restrict__ tpair, const int* __restrict__ bucket_base,
             float* __restrict__ dinv, int* __restrict__ row_ptr,
             int N, int E, int shift) {
  __shared__ int lcnt[1024];
  __shared__ int lscan[256];
  int b = blockIdx.x, t = threadIdx.x;
  int bs = 1 << shift, mask = bs - 1;
  for (int i = t; i < bs; i += 256) lcnt[i] = 0;
  __syncthreads();
  int r0 = bucket_base[b], r1 = bucket_base[b + 1];
  for (int e = r0 + t; e < r1; e += 256) atomicAdd(&lcnt[tpair[e].x & mask], 1);
  __syncthreads();
  if (bs == 256) {
    int v = lcnt[t];
    lscan[t] = v;
    __syncthreads();
    for (int off = 1; off < 256; off <<= 1) {
      int tt = (t >= off) ? lscan[t - off] : 0;
      __syncthreads();
      lscan[t] += tt;
      __syncthreads();
    }
    int node = (b << shift) + t;
    if (node < N) {
      row_ptr[node] = r0 + lscan[t] - v;
      dinv[node] = rsqrtf((float)(v + 1));   // +1 self-loop
      if (node == N - 1) row_ptr[N] = E;
    }
  } else {
    if (t == 0) {                            // fallback (not hit at N=100000)
      int acc = r0;
      for (int i = 0; i < bs; i++) {
        int node = (b << shift) + i;
        if (node < N) {
          row_ptr[node] = acc;
          dinv[node] = rsqrtf((float)(lcnt[i] + 1));
          if (node == N - 1) row_ptr[N] = E;
        }
        acc += lcnt[i];
      }
    }
  }
}

__global__ __launch_bounds__(256)
void k_csr2(const int2* __restrict__ tpair,
            const int* __restrict__ bucket_base, const int* __restrict__ row_ptr,
            int* __restrict__ col_src, int N, int shift) {
  __shared__ int lrp[1024];
  __shared__ int lfill[1024];
  int b = blockIdx.x, t = threadIdx.x;
  int bs = 1 << shift, mask = bs - 1;
  for (int i = t; i < bs; i += 256) {
    int node = (b << shift) + i;
    lrp[i] = row_ptr[node < N ? node : N];
    lfill[i] = 0;
  }
  __syncthreads();
  int r0 = bucket_base[b], r1 = bucket_base[b + 1];
  for (int e = r0 + t; e < r1; e += 256) {
    int2 pr = tpair[e];
    int dl = pr.x & mask;
    int p = lrp[dl] + atomicAdd(&lfill[dl], 1);
    col_src[p] = pr.y;
  }
}

// ------- W1 cast: W1bf[col][k] = bf16(W1[k][col]), padded to 112 cols -------
__global__ void k_w1cast(const float* __restrict__ W1, unsigned short* __restrict__ W1bf) {
  int i = blockIdx.x * 256 + threadIdx.x;
  if (i >= NPAD * FDIM) return;
  int col = i / FDIM, k = i % FDIM;
  float v = (col < H1) ? W1[k * H1 + col] : 0.f;
  W1bf[i] = (unsigned short)f2bf_bits(v);
}

// ------ GEMM1 (MFMA): t1p[r][c] = bf16( (x@W1)[r][c] * dinv[r] ) ------------
__global__ __launch_bounds__(512, 2)
void k_gemm1m(const float* __restrict__ x, const unsigned short* __restrict__ W1bf,
              const float* __restrict__ dinv, unsigned short* __restrict__ t1p, int n) {
  __shared__ unsigned short ws[NPAD * FDIM];   // [col][k] bf16, swizzled
  int tid = threadIdx.x;
  int lane = tid & 63, w = tid >> 6;
  int lr = lane & 15, lg = lane >> 4;
  int r0 = blockIdx.x * 128 + w * 16;
  int arow = r0 + lr;
  const float* xrow = x + (size_t)(arow < n ? arow : 0) * FDIM;

  // issue A loads first: 16 independent float4, in flight across the barrier
  float4 va[16];
#pragma unroll
  for (int s = 0; s < 8; ++s) {
    int kb = s * 32 + lg * 8;
    va[2 * s]     = *(const float4*)(xrow + kb);
    va[2 * s + 1] = *(const float4*)(xrow + kb + 4);
  }

  // stage W: 3584 16B-chunks, 7 per thread, swizzled
  for (int i = tid; i < NPAD * FDIM / 8; i += 512) {
    int col = i >> 5;          // 32 chunks per col
    int kc = i & 31;           // chunk = 8 k
    uint4 v = *(const uint4*)(W1bf + col * FDIM + kc * 8);
    unsigned addr = (unsigned)(col * 512 + kc * 16) ^ ((unsigned)(col & 7) << 4);
    *(uint4*)((char*)ws + addr) = v;
  }
  asm volatile("" ::: "memory");   // keep A loads issued above this point
  __syncthreads();

  bf16x8 af[8];
#pragma unroll
  for (int s = 0; s < 8; ++s) {
    uint4 au;
    au.x = pack_bf16(va[2 * s].x, va[2 * s].y);
    au.y = pack_bf16(va[2 * s].z, va[2 * s].w);
    au.z = pack_bf16(va[2 * s + 1].x, va[2 * s + 1].y);
    au.w = pack_bf16(va[2 * s + 1].z, va[2 * s + 1].w);
    af[s] = *(bf16x8*)&au;
  }

  f32x4 acc[7];
#pragma unroll
  for (int nt = 0; nt < 7; nt++) acc[nt] = (f32x4){0.f, 0.f, 0.f, 0.f};

#pragma unroll
  for (int s = 0; s < 8; ++s) {
    int kb = s * 32 + lg * 8;
#pragma unroll
    for (int nt = 0; nt < 7; nt++) {
      int col = nt * 16 + lr;
      unsigned addr = (unsigned)(col * 512 + kb * 2) ^ ((unsigned)(col & 7) << 4);
      bf16x8 b = *(bf16x8*)((char*)ws + addr);
      acc[nt] = __builtin_amdgcn_mfma_f32_16x16x32_bf16(af[s], b, acc[nt], 0, 0, 0);
    }
  }

  // epilogue: D col = lane&15, row = (lane>>4)*4 + r
  float dv[4];
  int rbase = r0 + lg * 4;
#pragma unroll
  for (int r = 0; r < 4; r++) dv[r] = (rbase + r < n) ? dinv[rbase + r] : 0.f;
#pragma unroll
  for (int nt = 0; nt < 7; nt++) {
    int col = nt * 16 + lr;
    if (col < H1) {
#pragma unroll
      for (int r = 0; r < 4; r++) {
        int row = rbase + r;
        if (row < n)
          t1p[(size_t)row * H1 + col] = (unsigned short)f2bf_bits(acc[nt][r] * dv[r]);
      }
    }
  }
}

// ---- agg1: uniform wid via readfirstlane -> scalar CSR walk ----------------
__global__ __launch_bounds__(256)
void k_agg1(const unsigned* __restrict__ t1p, const int* __restrict__ row_ptr,
            const int* __restrict__ col_src, const float* __restrict__ dinv,
            const float* __restrict__ b1, unsigned* __restrict__ h, int n) {
  int wv = __builtin_amdgcn_readfirstlane((int)(threadIdx.x >> 6));  // uniform
  int wid = blockIdx.x * 4 + wv;
  if (wid >= n) return;
  int lane = threadIdx.x & 63;
  if (lane >= 50) return;
  int beg = row_ptr[wid], end = row_ptr[wid + 1];   // scalar loads
  float a0 = 0.f, a1 = 0.f;
  int e = beg;
  for (; e + 8 <= end; e += 8) {
    int s0 = col_src[e + 0], s1 = col_src[e + 1];   // uniform -> s_load
    int s2 = col_src[e + 2], s3 = col_src[e + 3];
    int s4 = col_src[e + 4], s5 = col_src[e + 5];
    int s6 = col_src[e + 6], s7 = col_src[e + 7];
    unsigned u0 = t1p[(size_t)s0 * 50 + lane];
    unsigned u1 = t1p[(size_t)s1 * 50 + lane];
    unsigned u2 = t1p[(size_t)s2 * 50 + lane];
    unsigned u3 = t1p[(size_t)s3 * 50 + lane];
    unsigned u4 = t1p[(size_t)s4 * 50 + lane];
    unsigned u5 = t1p[(size_t)s5 * 50 + lane];
    unsigned u6 = t1p[(size_t)s6 * 50 + lane];
    unsigned u7 = t1p[(size_t)s7 * 50 + lane];
    a0 += bf_lo(u0); a1 += bf_hi(u0);
    a0 += bf_lo(u1); a1 += bf_hi(u1);
    a0 += bf_lo(u2); a1 += bf_hi(u2);
    a0 += bf_lo(u3); a1 += bf_hi(u3);
    a0 += bf_lo(u4); a1 += bf_hi(u4);
    a0 += bf_lo(u5); a1 += bf_hi(u5);
    a0 += bf_lo(u6); a1 += bf_hi(u6);
    a0 += bf_lo(u7); a1 += bf_hi(u7);
  }
  int rem = end - e;          // uniform, 0..7
  if (rem > 0) {
    int last = end - 1;
    int i1 = (e + 1 < end) ? e + 1 : last;
    int i2 = (e + 2 < end) ? e + 2 : last;
    int i3 = (e + 3 < end) ? e + 3 : last;
    int i4 = (e + 4 < end) ? e + 4 : last;
    int i5 = (e + 5 < end) ? e + 5 : last;
    int i6 = (e + 6 < end) ? e + 6 : last;
    int s0 = col_src[e],  s1 = col_src[i1], s2 = col_src[i2], s3 = col_src[i3];
    int s4 = col_src[i4], s5 = col_src[i5], s6 = col_src[i6];
    unsigned u0 = t1p[(size_t)s0 * 50 + lane];
    unsigned u1 = (rem > 1) ? t1p[(size_t)s1 * 50 + lane] : 0u;
    unsigned u2 = (rem > 2) ? t1p[(size_t)s2 * 50 + lane] : 0u;
    unsigned u3 = (rem > 3) ? t1p[(size_t)s3 * 50 + lane] : 0u;
    unsigned u4 = (rem > 4) ? t1p[(size_t)s4 * 50 + lane] : 0u;
    unsigned u5 = (rem > 5) ? t1p[(size_t)s5 * 50 + lane] : 0u;
    unsigned u6 = (rem > 6) ? t1p[(size_t)s6 * 50 + lane] : 0u;
    a0 += bf_lo(u0); a1 += bf_hi(u0);
    a0 += bf_lo(u1); a1 += bf_hi(u1);
    a0 += bf_lo(u2); a1 += bf_hi(u2);
    a0 += bf_lo(u3); a1 += bf_hi(u3);
    a0 += bf_lo(u4); a1 += bf_hi(u4);
    a0 += bf_lo(u5); a1 += bf_hi(u5);
    a0 += bf_lo(u6); a1 += bf_hi(u6);
  }
  unsigned su = t1p[(size_t)wid * 50 + lane];
  a0 += bf_lo(su);
  a1 += bf_hi(su);
  float dv = dinv[wid];   // scalar load
  float v0 = fmaxf(dv * a0 + b1[2 * lane], 0.f);
  float v1 = fmaxf(dv * a1 + b1[2 * lane + 1], 0.f);
  h[(size_t)wid * 50 + lane] = pack_bf16(v0, v1);
}

// ------ GEMM2: t2p = bf16( (h @ W2) * dinv )  (N x 100 x 16) ----------------
__global__ __launch_bounds__(256)
void k_gemm2(const unsigned* __restrict__ h, const float* __restrict__ W2,
             const float* __restrict__ dinv, unsigned* __restrict__ t2p, int n) {
  __shared__ alignas(16) float w2s[100][16];
  __shared__ float hs[64][101];
  int tid = threadIdx.x;
  int r0 = blockIdx.x * 64;
  for (int idx = tid; idx < H1 * H2; idx += 256) w2s[idx / 16][idx % 16] = W2[idx];
  for (int idx = tid; idx < 64 * 50; idx += 256) {
    int row = idx / 50, u = idx % 50;
    int gr = r0 + row;
    unsigned v = 0;
    if (gr < n) v = h[(size_t)gr * 50 + u];
    hs[row][2 * u + 0] = bf_lo(v);
    hs[row][2 * u + 1] = bf_hi(v);
  }
  __syncthreads();
  int r = tid & 63, cg = tid >> 6;
  float ax = 0.f, ay = 0.f, az = 0.f, aw = 0.f;
#pragma unroll 4
  for (int k = 0; k < H1; ++k) {
    float a = hs[r][k];
    float4 w = *(const float4*)&w2s[k][cg * 4];
    ax += a * w.x; ay += a * w.y; az += a * w.z; aw += a * w.w;
  }
  int gr = r0 + r;
  if (gr < n) {
    float dv = dinv[gr];
    unsigned u0 = pack_bf16(ax * dv, ay * dv);
    unsigned u1 = pack_bf16(az * dv, aw * dv);
    *(uint2*)(t2p + (size_t)gr * 8 + cg * 2) = make_uint2(u0, u1);
  }
}

// ------- agg2 + bias + relu + row-normalize: embb (N x 16, bf16 packed) -----
__global__ __launch_bounds__(256)
void k_agg2(const unsigned* __restrict__ t2p, const int* __restrict__ row_ptr,
            const int* __restrict__ col_src, const float* __restrict__ dinv,
            const float* __restrict__ b2, unsigned* __restrict__ embb, int n) {
  int wv = __builtin_amdgcn_readfirstlane((int)(threadIdx.x >> 6));  // uniform
  int wid = blockIdx.x * 4 + wv;
  if (wid >= n) return;
  int lane = threadIdx.x & 63;
  int es = lane >> 3, c = lane & 7;
  int beg = row_ptr[wid], end = row_ptr[wid + 1];   // scalar loads
  float a0 = 0.f, a1 = 0.f;
  for (int e = beg + es; e < end; e += 8) {
    int s = col_src[e];
    unsigned u = t2p[(size_t)s * 8 + c];
    a0 += bf_lo(u);
    a1 += bf_hi(u);
  }
  a0 += __shfl_xor(a0, 8, 64);  a1 += __shfl_xor(a1, 8, 64);
  a0 += __shfl_xor(a0, 16, 64); a1 += __shfl_xor(a1, 16, 64);
  a0 += __shfl_xor(a0, 32, 64); a1 += __shfl_xor(a1, 32, 64);
  unsigned su = t2p[(size_t)wid * 8 + c];
  a0 += bf_lo(su);
  a1 += bf_hi(su);
  float dv = dinv[wid];
  float v0 = fmaxf(dv * a0 + b2[2 * c + 0], 0.f);
  float v1 = fmaxf(dv * a1 + b2[2 * c + 1], 0.f);
  float n2 = v0 * v0 + v1 * v1;
  n2 += __shfl_xor(n2, 1, 64);
  n2 += __shfl_xor(n2, 2, 64);
  n2 += __shfl_xor(n2, 4, 64);
  float scale = 1.f / fmaxf(sqrtf(n2), 1.f);
  if (es == 0) {
    embb[(size_t)wid * 8 + c] = pack_bf16(v0 * scale, v1 * scale);  // bf16 table: 3.2MB, L2-fits
  }
}

// ---- scorer B-fragment precompute: one-time, 64 threads ----
__global__ void k_sprep(const float* __restrict__ l1W, uint4* __restrict__ Bt) {
  int lane = threadIdx.x;   // 0..63
  int lr = lane & 15, lg = lane >> 4;
  float wb[16];
#pragma unroll
  for (int i = 0; i < 8; i++) {
    int k0 = lg * 8 + i;
    wb[i] = (lr < 25) ? l1W[k0 * 25 + lr] : 0.f;
    int k1 = 32 + lg * 8 + i;
    wb[8 + i] = (lr < 25 && k1 < 41) ? l1W[k1 * 25 + lr] : 0.f;
  }
  int j1 = 16 + lr;
  float wb2[16];
#pragma unroll
  for (int i = 0; i < 8; i++) {
    int k0 = lg * 8 + i;
    wb2[i] = (j1 < 25) ? l1W[k0 * 25 + j1] : 0.f;
    int k1 = 32 + lg * 8 + i;
    wb2[8 + i] = (j1 < 25 && k1 < 41) ? l1W[k1 * 25 + j1] : 0.f;
  }
  uint4 B00, B01, B10, B11;
  B00.x = pack_bf16(wb[0], wb[1]);  B00.y = pack_bf16(wb[2], wb[3]);
  B00.z = pack_bf16(wb[4], wb[5]);  B00.w = pack_bf16(wb[6], wb[7]);
  B01.x = pack_bf16(wb[8], wb[9]);  B01.y = pack_bf16(wb[10], wb[11]);
  B01.z = pack_bf16(wb[12], wb[13]); B01.w = pack_bf16(wb[14], wb[15]);
  B10.x = pack_bf16(wb2[0], wb2[1]); B10.y = pack_bf16(wb2[2], wb2[3]);
  B10.z = pack_bf16(wb2[4], wb2[5]); B10.w = pack_bf16(wb2[6], wb2[7]);
  B11.x = pack_bf16(wb2[8], wb2[9]); B11.y = pack_bf16(wb2[10], wb2[11]);
  B11.z = pack_bf16(wb2[12], wb2[13]); B11.w = pack_bf16(wb2[14], wb2[15]);
  Bt[lane * 4 + 0] = B00;
  Bt[lane * 4 + 1] = B01;
  Bt[lane * 4 + 2] = B10;
  Bt[lane * 4 + 3] = B11;
}

// ------ edge scorer v7: Bt-MFMA, 4 tiles (64 edges) per wave, bf16 emb ------
// Four independent te->embb->PI->pack->MFMA chains per wave; launch_bounds
// (256,4) keeps VGPR cap ~128 so all chains' loads stay in flight.
__global__ __launch_bounds__(256, 4)
void k_score(const unsigned* __restrict__ embb, const int* __restrict__ te,
             const float* __restrict__ PI, const uint4* __restrict__ Bt,
             const float* __restrict__ l1b, const float* __restrict__ lW,
             const float* __restrict__ lb, float* __restrict__ out, int ned) {
  int tid = threadIdx.x;
  int lane = tid & 63, w = tid >> 6;
  int lr = lane & 15, lg = lane >> 4;
  int e0 = blockIdx.x * 256 + w * 64;    // wave: edges [e0, e0+64)
  int ec[4];
#pragma unroll
  for (int t = 0; t < 4; t++) {
    int e = e0 + t * 16 + lr;
    ec[t] = (e < ned) ? e : 0;
  }

  uint4 B00 = Bt[lane * 4 + 0];
  uint4 B01 = Bt[lane * 4 + 1];
  uint4 B10 = Bt[lane * 4 + 2];
  uint4 B11 = Bt[lane * 4 + 3];

  uint4 A0[4], A1[4];
#pragma unroll
  for (int t = 0; t < 4; t++) {
    A0[t] = (uint4){0u, 0u, 0u, 0u};
    A1[t] = (uint4){0u, 0u, 0u, 0u};
  }

  if (lg < 2) {
    int2 uv[4];
#pragma unroll
    for (int t = 0; t < 4; t++) uv[t] = *(const int2*)(te + 2 * (size_t)ec[t]);
    uint4 uu[4], vv[4];
#pragma unroll
    for (int t = 0; t < 4; t++) {
      uu[t] = *(const uint4*)(embb + (size_t)uv[t].x * 8 + lg * 4);
      vv[t] = *(const uint4*)(embb + (size_t)uv[t].y * 8 + lg * 4);
    }
#pragma unroll
    for (int t = 0; t < 4; t++) {
      A0[t].x = sqd_pair(uu[t].x, vv[t].x);
      A0[t].y = sqd_pair(uu[t].y, vv[t].y);
      A0[t].z = sqd_pair(uu[t].z, vv[t].z);
      A0[t].w = sqd_pair(uu[t].w, vv[t].w);
    }
    if (lg == 0) {  // A1: k=32..39 -> PI[16..23]
#pragma unroll
      for (int t = 0; t < 4; t++) {
        const float* pie = PI + (size_t)ec[t] * 25;
        f32x4a p0 = *(const f32x4a*)(pie + 16);
        f32x4a p1 = *(const f32x4a*)(pie + 20);
        A1[t].x = pack_bf16(p0[0], p0[1]); A1[t].y = pack_bf16(p0[2], p0[3]);
        A1[t].z = pack_bf16(p1[0], p1[1]); A1[t].w = pack_bf16(p1[2], p1[3]);
      }
    } else {        // A1: k=40 -> PI[24]
#pragma unroll
      for (int t = 0; t < 4; t++) {
        A1[t].x = pack_bf16(PI[(size_t)ec[t] * 25 + 24], 0.f);
      }
    }
  } else {
#pragma unroll
    for (int t = 0; t < 4; t++) {
      const float* pp = PI + (size_t)ec[t] * 25 + (lg - 2) * 8;  // lg2->PI[0..7], lg3->PI[8..15]
      f32x4a p0 = *(const f32x4a*)(pp);
      f32x4a p1 = *(const f32x4a*)(pp + 4);
      A0[t].x = pack_bf16(p0[0], p0[1]); A0[t].y = pack_bf16(p0[2], p0[3]);
      A0[t].z = pack_bf16(p1[0], p1[1]); A0[t].w = pack_bf16(p1[2], p1[3]);
    }
  }

  f32x4 acc0[4], acc1[4];
#pragma unroll
  for (int t = 0; t < 4; t++) {
    acc0[t] = (f32x4){0.f, 0.f, 0.f, 0.f};
    acc1[t] = (f32x4){0.f, 0.f, 0.f, 0.f};
  }
#pragma unroll
  for (int t = 0; t < 4; t++)
    acc0[t] = __builtin_amdgcn_mfma_f32_16x16x32_bf16(*(bf16x8*)&A0[t], *(bf16x8*)&B00, acc0[t], 0, 0, 0);
#pragma unroll
  for (int t = 0; t < 4; t++)
    acc0[t] = __builtin_amdgcn_mfma_f32_16x16x32_bf16(*(bf16x8*)&A1[t], *(bf16x8*)&B01, acc0[t], 0, 0, 0);
#pragma unroll
  for (int t = 0; t < 4; t++)
    acc1[t] = __builtin_amdgcn_mfma_f32_16x16x32_bf16(*(bf16x8*)&A0[t], *(bf16x8*)&B10, acc1[t], 0, 0, 0);
#pragma unroll
  for (int t = 0; t < 4; t++)
    acc1[t] = __builtin_amdgcn_mfma_f32_16x16x32_bf16(*(bf16x8*)&A1[t], *(bf16x8*)&B11, acc1[t], 0, 0, 0);

  // ---- epilogue: leaky-relu + 2nd layer, reduce over j (lr lanes) ----
  int j1 = 16 + lr;
  float bj0 = l1b[lr];
  float wj0 = lW[lr];
  float bj1 = (j1 < 25) ? l1b[j1] : 0.f;
  float wj1 = (j1 < 25) ? lW[j1] : 0.f;
  float lbv = lb[0];

  float part[4][4];
#pragma unroll
  for (int t = 0; t < 4; t++) {
#pragma unroll
    for (int r = 0; r < 4; r++) {
      float x0 = acc0[t][r] + bj0;
      x0 = (x0 > 0.f) ? x0 : 0.2f * x0;
      float x1 = acc1[t][r] + bj1;
      x1 = (x1 > 0.f) ? x1 : 0.2f * x1;
      part[t][r] = x0 * wj0 + ((j1 < 25) ? x1 * wj1 : 0.f);
    }
  }
#pragma unroll
  for (int t = 0; t < 4; t++) {
#pragma unroll
    for (int r = 0; r < 4; r++) {
      part[t][r] += __shfl_xor(part[t][r], 1, 64);
      part[t][r] += __shfl_xor(part[t][r], 2, 64);
      part[t][r] += __shfl_xor(part[t][r], 4, 64);
      part[t][r] += __shfl_xor(part[t][r], 8, 64);
    }
  }
  if (lr == 0) {
#pragma unroll
    for (int t = 0; t < 4; t++) {
#pragma unroll
      for (int r = 0; r < 4; r++) {
        int eo = e0 + t * 16 + lg * 4 + r;
        if (eo < ned) {
          float s = fminf(fabsf(part[t][r] + lbv), 40.f);
          out[eo] = 1.f / (1.f + __expf(-(2.f - s)));
        }
      }
    }
  }
}

// ---------------- launch -----------------------------------------------------
extern "C" void kernel_launch(void* const* d_in, const int* in_sizes, int n_in,
                              void* d_out, int out_size, void* d_ws, size_t ws_size,
                              hipStream_t stream) {
  const float* x   = (const float*)d_in[0];
  const int*   ei  = (const int*)d_in[1];
  const int*   te  = (const int*)d_in[2];
  const float* PI  = (const float*)d_in[3];
  const float* W1  = (const float*)d_in[4];
  const float* b1  = (const float*)d_in[5];
  const float* W2  = (const float*)d_in[6];
  const float* b2  = (const float*)d_in[7];
  const float* l1W = (const float*)d_in[8];
  const float* l1b = (const float*)d_in[9];
  const float* lW  = (const float*)d_in[10];
  const float* lb  = (const float*)d_in[11];
  float* out = (float*)d_out;

  int h1 = in_sizes[5];            // 100
  int F  = in_sizes[4] / h1;       // 256
  int N  = in_sizes[0] / F;        // 100000
  int E  = in_sizes[1] / 2;        // 1600000
  int ED = in_sizes[2] / 2;        // 1000000

  const int* src  = ei;
  const int* dstp = ei + E;

  int shift = 8;
  while ((((size_t)N + ((size_t)1 << shift) - 1) >> shift) > 512) shift++;
  int nbuc = (N + (1 << shift) - 1) >> shift;

  size_t off = 0;
  auto alloc = [&](size_t bytes) -> void* {
    void* p = (char*)d_ws + off;
    off += (bytes + 255) & ~(size_t)255;
    return p;
  };
  float*          dinv     = (float*)alloc((size_t)N * 4);
  int*            row_ptr  = (int*)alloc((size_t)(N + 1) * 4);
  int*            bcnt     = (int*)alloc(512 * 4);
  int*            bbase    = (int*)alloc(520 * 4);
  int*            bfill    = (int*)alloc(512 * 4);
  int*            col_src  = (int*)alloc((size_t)E * 4);
  unsigned short* W1bf     = (unsigned short*)alloc((size_t)NPAD * FDIM * 2);
  uint4*          Bt       = (uint4*)alloc(64 * 4 * 16);
  unsigned*       t1p      = (unsigned*)alloc((size_t)N * 50 * 4 + 256);
  unsigned*       h        = (unsigned*)alloc((size_t)N * 50 * 4);
  unsigned*       t2p      = (unsigned*)alloc((size_t)N * 8 * 4);
  unsigned*       embb     = (unsigned*)alloc((size_t)N * 8 * 4);   // bf16 packed

  int2* tpair = (int2*)h;          // temp binned edges alias h (dead until agg1)

  int nwb = (E + BINCH - 1) / BINCH;

  hipMemsetAsync(bcnt, 0, 512 * 4, stream);
  k_bincnt<<<nwb, 256, 0, stream>>>(dstp, bcnt, E, shift);
  k_bscan<<<1, 512, 0, stream>>>(bcnt, bbase, bfill, nbuc, E);
  k_binwrite<<<nwb, 256, 0, stream>>>(src, dstp, bfill, tpair, E, shift);
  k_deg2s<<<nbuc, 256, 0, stream>>>(tpair, bbase, dinv, row_ptr, N, E, shift);
  k_csr2<<<nbuc, 256, 0, stream>>>(tpair, bbase, row_ptr, col_src, N, shift);
  k_w1cast<<<(NPAD * FDIM + 255) / 256, 256, 0, stream>>>(W1, W1bf);
  k_sprep<<<1, 64, 0, stream>>>(l1W, Bt);
  k_gemm1m<<<(N + 127) / 128, 512, 0, stream>>>(x, W1bf, dinv, (unsigned short*)t1p, N);
  k_agg1<<<(int)(((size_t)N * 64 + 255) / 256), 256, 0, stream>>>(t1p, row_ptr, col_src, dinv, b1, h, N);
  k_gemm2<<<(N + 63) / 64, 256, 0, stream>>>(h, W2, dinv, t2p, N);
  k_agg2<<<(int)(((size_t)N * 64 + 255) / 256), 256, 0, stream>>>(t2p, row_ptr, col_src, dinv, b2, embb, N);
  k_score<<<(ED + 255) / 256, 256, 0, stream>>>(embb, te, PI, Bt, l1b, lW, lb, out, ED);
}

// Round 16
// 275.372 us; speedup vs baseline: 1.0015x; 1.0015x over previous
//
#include <hip/hip_runtime.h>
#include <hip/hip_bf16.h>
#include <math.h>

#define H1 100
#define H2 16
#define FDIM 256
#define NPAD 112   // H1 padded to 7*16
#define BINCH 4096 // edges per binning workgroup

typedef __attribute__((ext_vector_type(8))) short bf16x8;
typedef __attribute__((ext_vector_type(4))) float f32x4;
typedef float f32x4a __attribute__((ext_vector_type(4), aligned(4)));  // 4B-aligned vec load

// ---- bf16 pack/unpack helpers ----
__device__ __forceinline__ float bf_lo(unsigned u) { return __uint_as_float(u << 16); }
__device__ __forceinline__ float bf_hi(unsigned u) { return __uint_as_float(u & 0xffff0000u); }
__device__ __forceinline__ unsigned f2bf_bits(float f) {
  unsigned x = __float_as_uint(f);
  return (x + 0x7fffu + ((x >> 16) & 1u)) >> 16;   // round-nearest-even
}
// HW packed convert: v_cvt_pk_bf16_f32 (1 instr)
__device__ __forceinline__ unsigned pack_bf16(float a, float b) {
  __hip_bfloat162 h = __float22bfloat162_rn(make_float2(a, b));
  unsigned u;
  __builtin_memcpy(&u, &h, 4);
  return u;
}
// (u-v)^2 for a packed bf16 pair -> packed bf16 pair
__device__ __forceinline__ unsigned sqd_pair(unsigned u, unsigned v) {
  float d0 = bf_lo(u) - bf_lo(v);
  float d1 = bf_hi(u) - bf_hi(v);
  return pack_bf16(d0 * d0, d1 * d1);
}

// ============ CSR build via bucket binning ==========
__global__ __launch_bounds__(256)
void k_bincnt(const int* __restrict__ dst, int* __restrict__ bucket_cnt,
              int E, int shift) {
  __shared__ int lcnt[512];
  int t = threadIdx.x;
  for (int i = t; i < 512; i += 256) lcnt[i] = 0;
  __syncthreads();
  int base = blockIdx.x * BINCH;
#pragma unroll
  for (int i = 0; i < 16; i++) {
    int e = base + t + i * 256;
    if (e < E) atomicAdd(&lcnt[dst[e] >> shift], 1);
  }
  __syncthreads();
  for (int b = t; b < 512; b += 256) {
    int c = lcnt[b];
    if (c > 0) atomicAdd(&bucket_cnt[b], c);
  }
}

__global__ void k_bscan(const int* __restrict__ bucket_cnt, int* __restrict__ bucket_base,
                        int* __restrict__ bucket_fill, int nbuc, int E) {
  __shared__ int s[512];
  int tid = threadIdx.x;
  int v = (tid < nbuc) ? bucket_cnt[tid] : 0;
  s[tid] = v;
  __syncthreads();
  for (int off = 1; off < 512; off <<= 1) {
    int tt = (tid >= off) ? s[tid - off] : 0;
    __syncthreads();
    s[tid] += tt;
    __syncthreads();
  }
  if (tid < nbuc) { int ex = s[tid] - v; bucket_base[tid] = ex; bucket_fill[tid] = ex; }
  if (tid == 0) bucket_base[nbuc] = E;
}

// pass 3: write (dst,src) int2 pairs binned by bucket (single 8B store/edge)
__global__ __launch_bounds__(256)
void k_binwrite(const int* __restrict__ src, const int* __restrict__ dst,
                int* __restrict__ bucket_fill, int2* __restrict__ tpair,
                int E, int shift) {
  __shared__ int lcnt[512];
  __shared__ int loff[512];
  int t = threadIdx.x;
  for (int i = t; i < 512; i += 256) lcnt[i] = 0;
  __syncthreads();
  int base = blockIdx.x * BINCH;
  int d[16], s_[16];
#pragma unroll
  for (int i = 0; i < 16; i++) {
    int e = base + t + i * 256;
    if (e < E) {
      d[i] = dst[e]; s_[i] = src[e];
      atomicAdd(&lcnt[d[i] >> shift], 1);
    } else d[i] = -1;
  }
  __syncthreads();
  for (int b = t; b < 512; b += 256) {
    int c = lcnt[b];
    loff[b] = (c > 0) ? atomicAdd(&bucket_fill[b], c) : 0;
  }
  __syncthreads();
#pragma unroll
  for (int i = 0; i < 16; i++) {
    if (d[i] >= 0) {
      int p = atomicAdd(&loff[d[i] >> shift], 1);
      tpair[p] = make_int2(d[i], s_[i]);
    }
  }
}

// pass 4: per-bucket degree histogram + IN-LDS exclusive scan -> row_ptr, dinv
__global__ __launch_bounds__(256)
void k_deg2s(const int2* __restrict__ tpair, const int* __restrict__ bucket_base,
             float* __restrict__ dinv, int* __restrict__ row_ptr,
             int N, int E, int shift) {
  __shared__ int lcnt[1024];
  __shared__ int lscan[256];
  int b = blockIdx.x, t = threadIdx.x;
  int bs = 1 << shift, mask = bs - 1;
  for (int i = t; i < bs; i += 256) lcnt[i] = 0;
  __syncthreads();
  int r0 = bucket_base[b], r1 = bucket_base[b + 1];
  for (int e = r0 + t; e < r1; e += 256) atomicAdd(&lcnt[tpair[e].x & mask], 1);
  __syncthreads();
  if (bs == 256) {
    int v = lcnt[t];
    lscan[t] = v;
    __syncthreads();
    for (int off = 1; off < 256; off <<= 1) {
      int tt = (t >= off) ? lscan[t - off] : 0;
      __syncthreads();
      lscan[t] += tt;
      __syncthreads();
    }
    int node = (b << shift) + t;
    if (node < N) {
      row_ptr[node] = r0 + lscan[t] - v;
      dinv[node] = rsqrtf((float)(v + 1));   // +1 self-loop
      if (node == N - 1) row_ptr[N] = E;
    }
  } else {
    if (t == 0) {                            // fallback (not hit at N=100000)
      int acc = r0;
      for (int i = 0; i < bs; i++) {
        int node = (b << shift) + i;
        if (node < N) {
          row_ptr[node] = acc;
          dinv[node] = rsqrtf((float)(lcnt[i] + 1));
          if (node == N - 1) row_ptr[N] = E;
        }
        acc += lcnt[i];
      }
    }
  }
}

__global__ __launch_bounds__(256)
void k_csr2(const int2* __restrict__ tpair,
            const int* __restrict__ bucket_base, const int* __restrict__ row_ptr,
            int* __restrict__ col_src, int N, int shift) {
  __shared__ int lrp[1024];
  __shared__ int lfill[1024];
  int b = blockIdx.x, t = threadIdx.x;
  int bs = 1 << shift, mask = bs - 1;
  for (int i = t; i < bs; i += 256) {
    int node = (b << shift) + i;
    lrp[i] = row_ptr[node < N ? node : N];
    lfill[i] = 0;
  }
  __syncthreads();
  int r0 = bucket_base[b], r1 = bucket_base[b + 1];
  for (int e = r0 + t; e < r1; e += 256) {
    int2 pr = tpair[e];
    int dl = pr.x & mask;
    int p = lrp[dl] + atomicAdd(&lfill[dl], 1);
    col_src[p] = pr.y;
  }
}

// ------- W1 cast: W1bf[col][k] = bf16(W1[k][col]), padded to 112 cols -------
__global__ void k_w1cast(const float* __restrict__ W1, unsigned short* __restrict__ W1bf) {
  int i = blockIdx.x * 256 + threadIdx.x;
  if (i >= NPAD * FDIM) return;
  int col = i / FDIM, k = i % FDIM;
  float v = (col < H1) ? W1[k * H1 + col] : 0.f;
  W1bf[i] = (unsigned short)f2bf_bits(v);
}

// ------ GEMM1 (MFMA): t1p[r][c] = bf16( (x@W1)[r][c] * dinv[r] ) ------------
__global__ __launch_bounds__(512, 2)
void k_gemm1m(const float* __restrict__ x, const unsigned short* __restrict__ W1bf,
              const float* __restrict__ dinv, unsigned short* __restrict__ t1p, int n) {
  __shared__ unsigned short ws[NPAD * FDIM];   // [col][k] bf16, swizzled
  int tid = threadIdx.x;
  int lane = tid & 63, w = tid >> 6;
  int lr = lane & 15, lg = lane >> 4;
  int r0 = blockIdx.x * 128 + w * 16;
  int arow = r0 + lr;
  const float* xrow = x + (size_t)(arow < n ? arow : 0) * FDIM;

  // issue A loads first: 16 independent float4, in flight across the barrier
  float4 va[16];
#pragma unroll
  for (int s = 0; s < 8; ++s) {
    int kb = s * 32 + lg * 8;
    va[2 * s]     = *(const float4*)(xrow + kb);
    va[2 * s + 1] = *(const float4*)(xrow + kb + 4);
  }

  // stage W: 3584 16B-chunks, 7 per thread, swizzled
  for (int i = tid; i < NPAD * FDIM / 8; i += 512) {
    int col = i >> 5;          // 32 chunks per col
    int kc = i & 31;           // chunk = 8 k
    uint4 v = *(const uint4*)(W1bf + col * FDIM + kc * 8);
    unsigned addr = (unsigned)(col * 512 + kc * 16) ^ ((unsigned)(col & 7) << 4);
    *(uint4*)((char*)ws + addr) = v;
  }
  asm volatile("" ::: "memory");   // keep A loads issued above this point
  __syncthreads();

  bf16x8 af[8];
#pragma unroll
  for (int s = 0; s < 8; ++s) {
    uint4 au;
    au.x = pack_bf16(va[2 * s].x, va[2 * s].y);
    au.y = pack_bf16(va[2 * s].z, va[2 * s].w);
    au.z = pack_bf16(va[2 * s + 1].x, va[2 * s + 1].y);
    au.w = pack_bf16(va[2 * s + 1].z, va[2 * s + 1].w);
    af[s] = *(bf16x8*)&au;
  }

  f32x4 acc[7];
#pragma unroll
  for (int nt = 0; nt < 7; nt++) acc[nt] = (f32x4){0.f, 0.f, 0.f, 0.f};

#pragma unroll
  for (int s = 0; s < 8; ++s) {
    int kb = s * 32 + lg * 8;
#pragma unroll
    for (int nt = 0; nt < 7; nt++) {
      int col = nt * 16 + lr;
      unsigned addr = (unsigned)(col * 512 + kb * 2) ^ ((unsigned)(col & 7) << 4);
      bf16x8 b = *(bf16x8*)((char*)ws + addr);
      acc[nt] = __builtin_amdgcn_mfma_f32_16x16x32_bf16(af[s], b, acc[nt], 0, 0, 0);
    }
  }

  // epilogue: D col = lane&15, row = (lane>>4)*4 + r
  float dv[4];
  int rbase = r0 + lg * 4;
#pragma unroll
  for (int r = 0; r < 4; r++) dv[r] = (rbase + r < n) ? dinv[rbase + r] : 0.f;
#pragma unroll
  for (int nt = 0; nt < 7; nt++) {
    int col = nt * 16 + lr;
    if (col < H1) {
#pragma unroll
      for (int r = 0; r < 4; r++) {
        int row = rbase + r;
        if (row < n)
          t1p[(size_t)row * H1 + col] = (unsigned short)f2bf_bits(acc[nt][r] * dv[r]);
      }
    }
  }
}

// ---- agg1: uniform wid via readfirstlane -> scalar CSR walk ----------------
__global__ __launch_bounds__(256)
void k_agg1(const unsigned* __restrict__ t1p, const int* __restrict__ row_ptr,
            const int* __restrict__ col_src, const float* __restrict__ dinv,
            const float* __restrict__ b1, unsigned* __restrict__ h, int n) {
  int wv = __builtin_amdgcn_readfirstlane((int)(threadIdx.x >> 6));  // uniform
  int wid = blockIdx.x * 4 + wv;
  if (wid >= n) return;
  int lane = threadIdx.x & 63;
  if (lane >= 50) return;
  int beg = row_ptr[wid], end = row_ptr[wid + 1];   // scalar loads
  float a0 = 0.f, a1 = 0.f;
  int e = beg;
  for (; e + 8 <= end; e += 8) {
    int s0 = col_src[e + 0], s1 = col_src[e + 1];   // uniform -> s_load
    int s2 = col_src[e + 2], s3 = col_src[e + 3];
    int s4 = col_src[e + 4], s5 = col_src[e + 5];
    int s6 = col_src[e + 6], s7 = col_src[e + 7];
    unsigned u0 = t1p[(size_t)s0 * 50 + lane];
    unsigned u1 = t1p[(size_t)s1 * 50 + lane];
    unsigned u2 = t1p[(size_t)s2 * 50 + lane];
    unsigned u3 = t1p[(size_t)s3 * 50 + lane];
    unsigned u4 = t1p[(size_t)s4 * 50 + lane];
    unsigned u5 = t1p[(size_t)s5 * 50 + lane];
    unsigned u6 = t1p[(size_t)s6 * 50 + lane];
    unsigned u7 = t1p[(size_t)s7 * 50 + lane];
    a0 += bf_lo(u0); a1 += bf_hi(u0);
    a0 += bf_lo(u1); a1 += bf_hi(u1);
    a0 += bf_lo(u2); a1 += bf_hi(u2);
    a0 += bf_lo(u3); a1 += bf_hi(u3);
    a0 += bf_lo(u4); a1 += bf_hi(u4);
    a0 += bf_lo(u5); a1 += bf_hi(u5);
    a0 += bf_lo(u6); a1 += bf_hi(u6);
    a0 += bf_lo(u7); a1 += bf_hi(u7);
  }
  int rem = end - e;          // uniform, 0..7
  if (rem > 0) {
    int last = end - 1;
    int i1 = (e + 1 < end) ? e + 1 : last;
    int i2 = (e + 2 < end) ? e + 2 : last;
    int i3 = (e + 3 < end) ? e + 3 : last;
    int i4 = (e + 4 < end) ? e + 4 : last;
    int i5 = (e + 5 < end) ? e + 5 : last;
    int i6 = (e + 6 < end) ? e + 6 : last;
    int s0 = col_src[e],  s1 = col_src[i1], s2 = col_src[i2], s3 = col_src[i3];
    int s4 = col_src[i4], s5 = col_src[i5], s6 = col_src[i6];
    unsigned u0 = t1p[(size_t)s0 * 50 + lane];
    unsigned u1 = (rem > 1) ? t1p[(size_t)s1 * 50 + lane] : 0u;
    unsigned u2 = (rem > 2) ? t1p[(size_t)s2 * 50 + lane] : 0u;
    unsigned u3 = (rem > 3) ? t1p[(size_t)s3 * 50 + lane] : 0u;
    unsigned u4 = (rem > 4) ? t1p[(size_t)s4 * 50 + lane] : 0u;
    unsigned u5 = (rem > 5) ? t1p[(size_t)s5 * 50 + lane] : 0u;
    unsigned u6 = (rem > 6) ? t1p[(size_t)s6 * 50 + lane] : 0u;
    a0 += bf_lo(u0); a1 += bf_hi(u0);
    a0 += bf_lo(u1); a1 += bf_hi(u1);
    a0 += bf_lo(u2); a1 += bf_hi(u2);
    a0 += bf_lo(u3); a1 += bf_hi(u3);
    a0 += bf_lo(u4); a1 += bf_hi(u4);
    a0 += bf_lo(u5); a1 += bf_hi(u5);
    a0 += bf_lo(u6); a1 += bf_hi(u6);
  }
  unsigned su = t1p[(size_t)wid * 50 + lane];
  a0 += bf_lo(su);
  a1 += bf_hi(su);
  float dv = dinv[wid];   // scalar load
  float v0 = fmaxf(dv * a0 + b1[2 * lane], 0.f);
  float v1 = fmaxf(dv * a1 + b1[2 * lane + 1], 0.f);
  h[(size_t)wid * 50 + lane] = pack_bf16(v0, v1);
}

// ------ GEMM2: t2p = bf16( (h @ W2) * dinv )  (N x 100 x 16) ----------------
__global__ __launch_bounds__(256)
void k_gemm2(const unsigned* __restrict__ h, const float* __restrict__ W2,
             const float* __restrict__ dinv, unsigned* __restrict__ t2p, int n) {
  __shared__ alignas(16) float w2s[100][16];
  __shared__ float hs[64][101];
  int tid = threadIdx.x;
  int r0 = blockIdx.x * 64;
  for (int idx = tid; idx < H1 * H2; idx += 256) w2s[idx / 16][idx % 16] = W2[idx];
  for (int idx = tid; idx < 64 * 50; idx += 256) {
    int row = idx / 50, u = idx % 50;
    int gr = r0 + row;
    unsigned v = 0;
    if (gr < n) v = h[(size_t)gr * 50 + u];
    hs[row][2 * u + 0] = bf_lo(v);
    hs[row][2 * u + 1] = bf_hi(v);
  }
  __syncthreads();
  int r = tid & 63, cg = tid >> 6;
  float ax = 0.f, ay = 0.f, az = 0.f, aw = 0.f;
#pragma unroll 4
  for (int k = 0; k < H1; ++k) {
    float a = hs[r][k];
    float4 w = *(const float4*)&w2s[k][cg * 4];
    ax += a * w.x; ay += a * w.y; az += a * w.z; aw += a * w.w;
  }
  int gr = r0 + r;
  if (gr < n) {
    float dv = dinv[gr];
    unsigned u0 = pack_bf16(ax * dv, ay * dv);
    unsigned u1 = pack_bf16(az * dv, aw * dv);
    *(uint2*)(t2p + (size_t)gr * 8 + cg * 2) = make_uint2(u0, u1);
  }
}

// ------- agg2 + bias + relu + row-normalize: embb (N x 16, bf16 packed) -----
__global__ __launch_bounds__(256)
void k_agg2(const unsigned* __restrict__ t2p, const int* __restrict__ row_ptr,
            const int* __restrict__ col_src, const float* __restrict__ dinv,
            const float* __restrict__ b2, unsigned* __restrict__ embb, int n) {
  int wv = __builtin_amdgcn_readfirstlane((int)(threadIdx.x >> 6));  // uniform
  int wid = blockIdx.x * 4 + wv;
  if (wid >= n) return;
  int lane = threadIdx.x & 63;
  int es = lane >> 3, c = lane & 7;
  int beg = row_ptr[wid], end = row_ptr[wid + 1];   // scalar loads
  float a0 = 0.f, a1 = 0.f;
  for (int e = beg + es; e < end; e += 8) {
    int s = col_src[e];
    unsigned u = t2p[(size_t)s * 8 + c];
    a0 += bf_lo(u);
    a1 += bf_hi(u);
  }
  a0 += __shfl_xor(a0, 8, 64);  a1 += __shfl_xor(a1, 8, 64);
  a0 += __shfl_xor(a0, 16, 64); a1 += __shfl_xor(a1, 16, 64);
  a0 += __shfl_xor(a0, 32, 64); a1 += __shfl_xor(a1, 32, 64);
  unsigned su = t2p[(size_t)wid * 8 + c];
  a0 += bf_lo(su);
  a1 += bf_hi(su);
  float dv = dinv[wid];
  float v0 = fmaxf(dv * a0 + b2[2 * c + 0], 0.f);
  float v1 = fmaxf(dv * a1 + b2[2 * c + 1], 0.f);
  float n2 = v0 * v0 + v1 * v1;
  n2 += __shfl_xor(n2, 1, 64);
  n2 += __shfl_xor(n2, 2, 64);
  n2 += __shfl_xor(n2, 4, 64);
  float scale = 1.f / fmaxf(sqrtf(n2), 1.f);
  if (es == 0) {
    embb[(size_t)wid * 8 + c] = pack_bf16(v0 * scale, v1 * scale);  // bf16 table: 3.2MB, L2-fits
  }
}

// ---- scorer B-fragment precompute: one-time, 64 threads ----
__global__ void k_sprep(const float* __restrict__ l1W, uint4* __restrict__ Bt) {
  int lane = threadIdx.x;   // 0..63
  int lr = lane & 15, lg = lane >> 4;
  float wb[16];
#pragma unroll
  for (int i = 0; i < 8; i++) {
    int k0 = lg * 8 + i;
    wb[i] = (lr < 25) ? l1W[k0 * 25 + lr] : 0.f;
    int k1 = 32 + lg * 8 + i;
    wb[8 + i] = (lr < 25 && k1 < 41) ? l1W[k1 * 25 + lr] : 0.f;
  }
  int j1 = 16 + lr;
  float wb2[16];
#pragma unroll
  for (int i = 0; i < 8; i++) {
    int k0 = lg * 8 + i;
    wb2[i] = (j1 < 25) ? l1W[k0 * 25 + j1] : 0.f;
    int k1 = 32 + lg * 8 + i;
    wb2[8 + i] = (j1 < 25 && k1 < 41) ? l1W[k1 * 25 + j1] : 0.f;
  }
  uint4 B00, B01, B10, B11;
  B00.x = pack_bf16(wb[0], wb[1]);  B00.y = pack_bf16(wb[2], wb[3]);
  B00.z = pack_bf16(wb[4], wb[5]);  B00.w = pack_bf16(wb[6], wb[7]);
  B01.x = pack_bf16(wb[8], wb[9]);  B01.y = pack_bf16(wb[10], wb[11]);
  B01.z = pack_bf16(wb[12], wb[13]); B01.w = pack_bf16(wb[14], wb[15]);
  B10.x = pack_bf16(wb2[0], wb2[1]); B10.y = pack_bf16(wb2[2], wb2[3]);
  B10.z = pack_bf16(wb2[4], wb2[5]); B10.w = pack_bf16(wb2[6], wb2[7]);
  B11.x = pack_bf16(wb2[8], wb2[9]); B11.y = pack_bf16(wb2[10], wb2[11]);
  B11.z = pack_bf16(wb2[12], wb2[13]); B11.w = pack_bf16(wb2[14], wb2[15]);
  Bt[lane * 4 + 0] = B00;
  Bt[lane * 4 + 1] = B01;
  Bt[lane * 4 + 2] = B10;
  Bt[lane * 4 + 3] = B11;
}

// ------ edge scorer v7: Bt-MFMA, 4 tiles (64 edges) per wave, bf16 emb ------
// Four independent te->embb->PI->pack->MFMA chains per wave; launch_bounds
// (256,4) keeps VGPR cap ~128 so all chains' loads stay in flight.
__global__ __launch_bounds__(256, 4)
void k_score(const unsigned* __restrict__ embb, const int* __restrict__ te,
             const float* __restrict__ PI, const uint4* __restrict__ Bt,
             const float* __restrict__ l1b, const float* __restrict__ lW,
             const float* __restrict__ lb, float* __restrict__ out, int ned) {
  int tid = threadIdx.x;
  int lane = tid & 63, w = tid >> 6;
  int lr = lane & 15, lg = lane >> 4;
  int e0 = blockIdx.x * 256 + w * 64;    // wave: edges [e0, e0+64)
  int ec[4];
#pragma unroll
  for (int t = 0; t < 4; t++) {
    int e = e0 + t * 16 + lr;
    ec[t] = (e < ned) ? e : 0;
  }

  uint4 B00 = Bt[lane * 4 + 0];
  uint4 B01 = Bt[lane * 4 + 1];
  uint4 B10 = Bt[lane * 4 + 2];
  uint4 B11 = Bt[lane * 4 + 3];

  uint4 A0[4], A1[4];
#pragma unroll
  for (int t = 0; t < 4; t++) {
    A0[t] = (uint4){0u, 0u, 0u, 0u};
    A1[t] = (uint4){0u, 0u, 0u, 0u};
  }

  if (lg < 2) {
    int2 uv[4];
#pragma unroll
    for (int t = 0; t < 4; t++) uv[t] = *(const int2*)(te + 2 * (size_t)ec[t]);
    uint4 uu[4], vv[4];
#pragma unroll
    for (int t = 0; t < 4; t++) {
      uu[t] = *(const uint4*)(embb + (size_t)uv[t].x * 8 + lg * 4);
      vv[t] = *(const uint4*)(embb + (size_t)uv[t].y * 8 + lg * 4);
    }
#pragma unroll
    for (int t = 0; t < 4; t++) {
      A0[t].x = sqd_pair(uu[t].x, vv[t].x);
      A0[t].y = sqd_pair(uu[t].y, vv[t].y);
      A0[t].z = sqd_pair(uu[t].z, vv[t].z);
      A0[t].w = sqd_pair(uu[t].w, vv[t].w);
    }
    if (lg == 0) {  // A1: k=32..39 -> PI[16..23]
#pragma unroll
      for (int t = 0; t < 4; t++) {
        const float* pie = PI + (size_t)ec[t] * 25;
        f32x4a p0 = *(const f32x4a*)(pie + 16);
        f32x4a p1 = *(const f32x4a*)(pie + 20);
        A1[t].x = pack_bf16(p0[0], p0[1]); A1[t].y = pack_bf16(p0[2], p0[3]);
        A1[t].z = pack_bf16(p1[0], p1[1]); A1[t].w = pack_bf16(p1[2], p1[3]);
      }
    } else {        // A1: k=40 -> PI[24]
#pragma unroll
      for (int t = 0; t < 4; t++) {
        A1[t].x = pack_bf16(PI[(size_t)ec[t] * 25 + 24], 0.f);
      }
    }
  } else {
#pragma unroll
    for (int t = 0; t < 4; t++) {
      const float* pp = PI + (size_t)ec[t] * 25 + (lg - 2) * 8;  // lg2->PI[0..7], lg3->PI[8..15]
      f32x4a p0 = *(const f32x4a*)(pp);
      f32x4a p1 = *(const f32x4a*)(pp + 4);
      A0[t].x = pack_bf16(p0[0], p0[1]); A0[t].y = pack_bf16(p0[2], p0[3]);
      A0[t].z = pack_bf16(p1[0], p1[1]); A0[t].w = pack_bf16(p1[2], p1[3]);
    }
  }

  f32x4 acc0[4], acc1[4];
#pragma unroll
  for (int t = 0; t < 4; t++) {
    acc0[t] = (f32x4){0.f, 0.f, 0.f, 0.f};
    acc1[t] = (f32x4){0.f, 0.f, 0.f, 0.f};
  }
#pragma unroll
  for (int t = 0; t < 4; t++)
    acc0[t] = __builtin_amdgcn_mfma_f32_16x16x32_bf16(*(bf16x8*)&A0[t], *(bf16x8*)&B00, acc0[t], 0, 0, 0);
#pragma unroll
  for (int t = 0; t < 4; t++)
    acc0[t] = __builtin_amdgcn_mfma_f32_16x16x32_bf16(*(bf16x8*)&A1[t], *(bf16x8*)&B01, acc0[t], 0, 0, 0);
#pragma unroll
  for (int t = 0; t < 4; t++)
    acc1[t] = __builtin_amdgcn_mfma_f32_16x16x32_bf16(*(bf16x8*)&A0[t], *(bf16x8*)&B10, acc1[t], 0, 0, 0);
#pragma unroll
  for (int t = 0; t < 4; t++)
    acc1[t] = __builtin_amdgcn_mfma_f32_16x16x32_bf16(*(bf16x8*)&A1[t], *(bf16x8*)&B11, acc1[t], 0, 0, 0);

  // ---- epilogue: leaky-relu + 2nd layer, reduce over j (lr lanes) ----
  int j1 = 16 + lr;
  float bj0 = l1b[lr];
  float wj0 = lW[lr];
  float bj1 = (j1 < 25) ? l1b[j1] : 0.f;
  float wj1 = (j1 < 25) ? lW[j1] : 0.f;
  float lbv = lb[0];

  float part[4][4];
#pragma unroll
  for (int t = 0; t < 4; t++) {
#pragma unroll
    for (int r = 0; r < 4; r++) {
      float x0 = acc0[t][r] + bj0;
      x0 = (x0 > 0.f) ? x0 : 0.2f * x0;
      float x1 = acc1[t][r] + bj1;
      x1 = (x1 > 0.f) ? x1 : 0.2f * x1;
      part[t][r] = x0 * wj0 + ((j1 < 25) ? x1 * wj1 : 0.f);
    }
  }
#pragma unroll
  for (int t = 0; t < 4; t++) {
#pragma unroll
    for (int r = 0; r < 4; r++) {
      part[t][r] += __shfl_xor(part[t][r], 1, 64);
      part[t][r] += __shfl_xor(part[t][r], 2, 64);
      part[t][r] += __shfl_xor(part[t][r], 4, 64);
      part[t][r] += __shfl_xor(part[t][r], 8, 64);
    }
  }
  if (lr == 0) {
#pragma unroll
    for (int t = 0; t < 4; t++) {
#pragma unroll
      for (int r = 0; r < 4; r++) {
        int eo = e0 + t * 16 + lg * 4 + r;
        if (eo < ned) {
          float s = fminf(fabsf(part[t][r] + lbv), 40.f);
          out[eo] = 1.f / (1.f + __expf(-(2.f - s)));
        }
      }
    }
  }
}

// ---------------- launch -----------------------------------------------------
extern "C" void kernel_launch(void* const* d_in, const int* in_sizes, int n_in,
                              void* d_out, int out_size, void* d_ws, size_t ws_size,
                              hipStream_t stream) {
  const float* x   = (const float*)d_in[0];
  const int*   ei  = (const int*)d_in[1];
  const int*   te  = (const int*)d_in[2];
  const float* PI  = (const float*)d_in[3];
  const float* W1  = (const float*)d_in[4];
  const float* b1  = (const float*)d_in[5];
  const float* W2  = (const float*)d_in[6];
  const float* b2  = (const float*)d_in[7];
  const float* l1W = (const float*)d_in[8];
  const float* l1b = (const float*)d_in[9];
  const float* lW  = (const float*)d_in[10];
  const float* lb  = (const float*)d_in[11];
  float* out = (float*)d_out;

  int h1 = in_sizes[5];            // 100
  int F  = in_sizes[4] / h1;       // 256
  int N  = in_sizes[0] / F;        // 100000
  int E  = in_sizes[1] / 2;        // 1600000
  int ED = in_sizes[2] / 2;        // 1000000

  const int* src  = ei;
  const int* dstp = ei + E;

  int shift = 8;
  while ((((size_t)N + ((size_t)1 << shift) - 1) >> shift) > 512) shift++;
  int nbuc = (N + (1 << shift) - 1) >> shift;

  size_t off = 0;
  auto alloc = [&](size_t bytes) -> void* {
    void* p = (char*)d_ws + off;
    off += (bytes + 255) & ~(size_t)255;
    return p;
  };
  float*          dinv     = (float*)alloc((size_t)N * 4);
  int*            row_ptr  = (int*)alloc((size_t)(N + 1) * 4);
  int*            bcnt     = (int*)alloc(512 * 4);
  int*            bbase    = (int*)alloc(520 * 4);
  int*            bfill    = (int*)alloc(512 * 4);
  int*            col_src  = (int*)alloc((size_t)E * 4);
  unsigned short* W1bf     = (unsigned short*)alloc((size_t)NPAD * FDIM * 2);
  uint4*          Bt       = (uint4*)alloc(64 * 4 * 16);
  unsigned*       t1p      = (unsigned*)alloc((size_t)N * 50 * 4 + 256);
  unsigned*       h        = (unsigned*)alloc((size_t)N * 50 * 4);
  unsigned*       t2p      = (unsigned*)alloc((size_t)N * 8 * 4);
  unsigned*       embb     = (unsigned*)alloc((size_t)N * 8 * 4);   // bf16 packed

  int2* tpair = (int2*)h;          // temp binned edges alias h (dead until agg1)

  int nwb = (E + BINCH - 1) / BINCH;

  hipMemsetAsync(bcnt, 0, 512 * 4, stream);
  k_bincnt<<<nwb, 256, 0, stream>>>(dstp, bcnt, E, shift);
  k_bscan<<<1, 512, 0, stream>>>(bcnt, bbase, bfill, nbuc, E);
  k_binwrite<<<nwb, 256, 0, stream>>>(src, dstp, bfill, tpair, E, shift);
  k_deg2s<<<nbuc, 256, 0, stream>>>(tpair, bbase, dinv, row_ptr, N, E, shift);
  k_csr2<<<nbuc, 256, 0, stream>>>(tpair, bbase, row_ptr, col_src, N, shift);
  k_w1cast<<<(NPAD * FDIM + 255) / 256, 256, 0, stream>>>(W1, W1bf);
  k_sprep<<<1, 64, 0, stream>>>(l1W, Bt);
  k_gemm1m<<<(N + 127) / 128, 512, 0, stream>>>(x, W1bf, dinv, (unsigned short*)t1p, N);
  k_agg1<<<(int)(((size_t)N * 64 + 255) / 256), 256, 0, stream>>>(t1p, row_ptr, col_src, dinv, b1, h, N);
  k_gemm2<<<(N + 63) / 64, 256, 0, stream>>>(h, W2, dinv, t2p, N);
  k_agg2<<<(int)(((size_t)N * 64 + 255) / 256), 256, 0, stream>>>(t2p, row_ptr, col_src, dinv, b2, embb, N);
  k_score<<<(ED + 255) / 256, 256, 0, stream>>>(embb, te, PI, Bt, l1b, lW, lb, out, ED);
}

// Round 17
// 272.494 us; speedup vs baseline: 1.0121x; 1.0106x over previous
//
#include <hip/hip_runtime.h>
#include <hip/hip_bf16.h>
#include <math.h>

#define H1 100
#define H2 16
#define FDIM 256
#define NPAD 112   // H1 padded to 7*16
#define BINCH 4096 // edges per binning workgroup

typedef __attribute__((ext_vector_type(8))) short bf16x8;
typedef __attribute__((ext_vector_type(4))) float f32x4;
typedef float f32x4a __attribute__((ext_vector_type(4), aligned(4)));  // 4B-aligned vec load

// ---- bf16 pack/unpack helpers ----
__device__ __forceinline__ float bf_lo(unsigned u) { return __uint_as_float(u << 16); }
__device__ __forceinline__ float bf_hi(unsigned u) { return __uint_as_float(u & 0xffff0000u); }
__device__ __forceinline__ unsigned f2bf_bits(float f) {
  unsigned x = __float_as_uint(f);
  return (x + 0x7fffu + ((x >> 16) & 1u)) >> 16;   // round-nearest-even
}
// HW packed convert: v_cvt_pk_bf16_f32 (1 instr)
__device__ __forceinline__ unsigned pack_bf16(float a, float b) {
  __hip_bfloat162 h = __float22bfloat162_rn(make_float2(a, b));
  unsigned u;
  __builtin_memcpy(&u, &h, 4);
  return u;
}
// (u-v)^2 for a packed bf16 pair -> packed bf16 pair
__device__ __forceinline__ unsigned sqd_pair(unsigned u, unsigned v) {
  float d0 = bf_lo(u) - bf_lo(v);
  float d1 = bf_hi(u) - bf_hi(v);
  return pack_bf16(d0 * d0, d1 * d1);
}

// ============ CSR build via bucket binning ==========
__global__ __launch_bounds__(256)
void k_bincnt(const int* __restrict__ dst, int* __restrict__ bucket_cnt,
              int E, int shift) {
  __shared__ int lcnt[512];
  int t = threadIdx.x;
  for (int i = t; i < 512; i += 256) lcnt[i] = 0;
  __syncthreads();
  int base = blockIdx.x * BINCH;
#pragma unroll
  for (int i = 0; i < 16; i++) {
    int e = base + t + i * 256;
    if (e < E) atomicAdd(&lcnt[dst[e] >> shift], 1);
  }
  __syncthreads();
  for (int b = t; b < 512; b += 256) {
    int c = lcnt[b];
    if (c > 0) atomicAdd(&bucket_cnt[b], c);
  }
}

__global__ void k_bscan(const int* __restrict__ bucket_cnt, int* __restrict__ bucket_base,
                        int* __restrict__ bucket_fill, int nbuc, int E) {
  __shared__ int s[512];
  int tid = threadIdx.x;
  int v = (tid < nbuc) ? bucket_cnt[tid] : 0;
  s[tid] = v;
  __syncthreads();
  for (int off = 1; off < 512; off <<= 1) {
    int tt = (tid >= off) ? s[tid - off] : 0;
    __syncthreads();
    s[tid] += tt;
    __syncthreads();
  }
  if (tid < nbuc) { int ex = s[tid] - v; bucket_base[tid] = ex; bucket_fill[tid] = ex; }
  if (tid == 0) bucket_base[nbuc] = E;
}

// pass 3: write (dst,src) int2 pairs binned by bucket (single 8B store/edge)
__global__ __launch_bounds__(256)
void k_binwrite(const int* __restrict__ src, const int* __restrict__ dst,
                int* __restrict__ bucket_fill, int2* __restrict__ tpair,
                int E, int shift) {
  __shared__ int lcnt[512];
  __shared__ int loff[512];
  int t = threadIdx.x;
  for (int i = t; i < 512; i += 256) lcnt[i] = 0;
  __syncthreads();
  int base = blockIdx.x * BINCH;
  int d[16], s_[16];
#pragma unroll
  for (int i = 0; i < 16; i++) {
    int e = base + t + i * 256;
    if (e < E) {
      d[i] = dst[e]; s_[i] = src[e];
      atomicAdd(&lcnt[d[i] >> shift], 1);
    } else d[i] = -1;
  }
  __syncthreads();
  for (int b = t; b < 512; b += 256) {
    int c = lcnt[b];
    loff[b] = (c > 0) ? atomicAdd(&bucket_fill[b], c) : 0;
  }
  __syncthreads();
#pragma unroll
  for (int i = 0; i < 16; i++) {
    if (d[i] >= 0) {
      int p = atomicAdd(&loff[d[i] >> shift], 1);
      tpair[p] = make_int2(d[i], s_[i]);
    }
  }
}

// pass 4: per-bucket degree histogram + IN-LDS exclusive scan -> row_ptr, dinv
__global__ __launch_bounds__(256)
void k_deg2s(const int2* __restrict__ tpair, const int* __restrict__ bucket_base,
             float* __restrict__ dinv, int* __restrict__ row_ptr,
             int N, int E, int shift) {
  __shared__ int lcnt[1024];
  __shared__ int lscan[256];
  int b = blockIdx.x, t = threadIdx.x;
  int bs = 1 << shift, mask = bs - 1;
  for (int i = t; i < bs; i += 256) lcnt[i] = 0;
  __syncthreads();
  int r0 = bucket_base[b], r1 = bucket_base[b + 1];
  for (int e = r0 + t; e < r1; e += 256) atomicAdd(&lcnt[tpair[e].x & mask], 1);
  __syncthreads();
  if (bs == 256) {
    int v = lcnt[t];
    lscan[t] = v;
    __syncthreads();
    for (int off = 1; off < 256; off <<= 1) {
      int tt = (t >= off) ? lscan[t - off] : 0;
      __syncthreads();
      lscan[t] += tt;
      __syncthreads();
    }
    int node = (b << shift) + t;
    if (node < N) {
      row_ptr[node] = r0 + lscan[t] - v;
      dinv[node] = rsqrtf((float)(v + 1));   // +1 self-loop
      if (node == N - 1) row_ptr[N] = E;
    }
  } else {
    if (t == 0) {                            // fallback (not hit at N=100000)
      int acc = r0;
      for (int i = 0; i < bs; i++) {
        int node = (b << shift) + i;
        if (node < N) {
          row_ptr[node] = acc;
          dinv[node] = rsqrtf((float)(lcnt[i] + 1));
          if (node == N - 1) row_ptr[N] = E;
        }
        acc += lcnt[i];
      }
    }
  }
}

__global__ __launch_bounds__(256)
void k_csr2(const int2* __restrict__ tpair,
            const int* __restrict__ bucket_base, const int* __restrict__ row_ptr,
            int* __restrict__ col_src, int N, int shift) {
  __shared__ int lrp[1024];
  __shared__ int lfill[1024];
  int b = blockIdx.x, t = threadIdx.x;
  int bs = 1 << shift, mask = bs - 1;
  for (int i = t; i < bs; i += 256) {
    int node = (b << shift) + i;
    lrp[i] = row_ptr[node < N ? node : N];
    lfill[i] = 0;
  }
  __syncthreads();
  int r0 = bucket_base[b], r1 = bucket_base[b + 1];
  for (int e = r0 + t; e < r1; e += 256) {
    int2 pr = tpair[e];
    int dl = pr.x & mask;
    int p = lrp[dl] + atomicAdd(&lfill[dl], 1);
    col_src[p] = pr.y;
  }
}

// ------- W1 cast: W1bf[col][k] = bf16(W1[k][col]), padded to 112 cols -------
__global__ void k_w1cast(const float* __restrict__ W1, unsigned short* __restrict__ W1bf) {
  int i = blockIdx.x * 256 + threadIdx.x;
  if (i >= NPAD * FDIM) return;
  int col = i / FDIM, k = i % FDIM;
  float v = (col < H1) ? W1[k * H1 + col] : 0.f;
  W1bf[i] = (unsigned short)f2bf_bits(v);
}

// ------ GEMM1 (MFMA): t1p[r][c] = bf16( (x@W1)[r][c] * dinv[r] ) ------------
__global__ __launch_bounds__(512, 2)
void k_gemm1m(const float* __restrict__ x, const unsigned short* __restrict__ W1bf,
              const float* __restrict__ dinv, unsigned short* __restrict__ t1p, int n) {
  __shared__ unsigned short ws[NPAD * FDIM];   // [col][k] bf16, swizzled
  int tid = threadIdx.x;
  int lane = tid & 63, w = tid >> 6;
  int lr = lane & 15, lg = lane >> 4;
  int r0 = blockIdx.x * 128 + w * 16;
  int arow = r0 + lr;
  const float* xrow = x + (size_t)(arow < n ? arow : 0) * FDIM;

  // issue A loads first: 16 independent float4, in flight across the barrier
  float4 va[16];
#pragma unroll
  for (int s = 0; s < 8; ++s) {
    int kb = s * 32 + lg * 8;
    va[2 * s]     = *(const float4*)(xrow + kb);
    va[2 * s + 1] = *(const float4*)(xrow + kb + 4);
  }

  // stage W: 3584 16B-chunks, 7 per thread, swizzled
  for (int i = tid; i < NPAD * FDIM / 8; i += 512) {
    int col = i >> 5;          // 32 chunks per col
    int kc = i & 31;           // chunk = 8 k
    uint4 v = *(const uint4*)(W1bf + col * FDIM + kc * 8);
    unsigned addr = (unsigned)(col * 512 + kc * 16) ^ ((unsigned)(col & 7) << 4);
    *(uint4*)((char*)ws + addr) = v;
  }
  asm volatile("" ::: "memory");   // keep A loads issued above this point
  __syncthreads();

  bf16x8 af[8];
#pragma unroll
  for (int s = 0; s < 8; ++s) {
    uint4 au;
    au.x = pack_bf16(va[2 * s].x, va[2 * s].y);
    au.y = pack_bf16(va[2 * s].z, va[2 * s].w);
    au.z = pack_bf16(va[2 * s + 1].x, va[2 * s + 1].y);
    au.w = pack_bf16(va[2 * s + 1].z, va[2 * s + 1].w);
    af[s] = *(bf16x8*)&au;
  }

  f32x4 acc[7];
#pragma unroll
  for (int nt = 0; nt < 7; nt++) acc[nt] = (f32x4){0.f, 0.f, 0.f, 0.f};

#pragma unroll
  for (int s = 0; s < 8; ++s) {
    int kb = s * 32 + lg * 8;
#pragma unroll
    for (int nt = 0; nt < 7; nt++) {
      int col = nt * 16 + lr;
      unsigned addr = (unsigned)(col * 512 + kb * 2) ^ ((unsigned)(col & 7) << 4);
      bf16x8 b = *(bf16x8*)((char*)ws + addr);
      acc[nt] = __builtin_amdgcn_mfma_f32_16x16x32_bf16(af[s], b, acc[nt], 0, 0, 0);
    }
  }

  // epilogue: D col = lane&15, row = (lane>>4)*4 + r
  float dv[4];
  int rbase = r0 + lg * 4;
#pragma unroll
  for (int r = 0; r < 4; r++) dv[r] = (rbase + r < n) ? dinv[rbase + r] : 0.f;
#pragma unroll
  for (int nt = 0; nt < 7; nt++) {
    int col = nt * 16 + lr;
    if (col < H1) {
#pragma unroll
      for (int r = 0; r < 4; r++) {
        int row = rbase + r;
        if (row < n)
          t1p[(size_t)row * H1 + col] = (unsigned short)f2bf_bits(acc[nt][r] * dv[r]);
      }
    }
  }
}

// ---- agg1: uniform wid via readfirstlane -> scalar CSR walk ----------------
__global__ __launch_bounds__(256)
void k_agg1(const unsigned* __restrict__ t1p, const int* __restrict__ row_ptr,
            const int* __restrict__ col_src, const float* __restrict__ dinv,
            const float* __restrict__ b1, unsigned* __restrict__ h, int n) {
  int wv = __builtin_amdgcn_readfirstlane((int)(threadIdx.x >> 6));  // uniform
  int wid = blockIdx.x * 4 + wv;
  if (wid >= n) return;
  int lane = threadIdx.x & 63;
  if (lane >= 50) return;
  int beg = row_ptr[wid], end = row_ptr[wid + 1];   // scalar loads
  float a0 = 0.f, a1 = 0.f;
  int e = beg;
  for (; e + 8 <= end; e += 8) {
    int s0 = col_src[e + 0], s1 = col_src[e + 1];   // uniform -> s_load
    int s2 = col_src[e + 2], s3 = col_src[e + 3];
    int s4 = col_src[e + 4], s5 = col_src[e + 5];
    int s6 = col_src[e + 6], s7 = col_src[e + 7];
    unsigned u0 = t1p[(size_t)s0 * 50 + lane];
    unsigned u1 = t1p[(size_t)s1 * 50 + lane];
    unsigned u2 = t1p[(size_t)s2 * 50 + lane];
    unsigned u3 = t1p[(size_t)s3 * 50 + lane];
    unsigned u4 = t1p[(size_t)s4 * 50 + lane];
    unsigned u5 = t1p[(size_t)s5 * 50 + lane];
    unsigned u6 = t1p[(size_t)s6 * 50 + lane];
    unsigned u7 = t1p[(size_t)s7 * 50 + lane];
    a0 += bf_lo(u0); a1 += bf_hi(u0);
    a0 += bf_lo(u1); a1 += bf_hi(u1);
    a0 += bf_lo(u2); a1 += bf_hi(u2);
    a0 += bf_lo(u3); a1 += bf_hi(u3);
    a0 += bf_lo(u4); a1 += bf_hi(u4);
    a0 += bf_lo(u5); a1 += bf_hi(u5);
    a0 += bf_lo(u6); a1 += bf_hi(u6);
    a0 += bf_lo(u7); a1 += bf_hi(u7);
  }
  int rem = end - e;          // uniform, 0..7
  if (rem > 0) {
    int last = end - 1;
    int i1 = (e + 1 < end) ? e + 1 : last;
    int i2 = (e + 2 < end) ? e + 2 : last;
    int i3 = (e + 3 < end) ? e + 3 : last;
    int i4 = (e + 4 < end) ? e + 4 : last;
    int i5 = (e + 5 < end) ? e + 5 : last;
    int i6 = (e + 6 < end) ? e + 6 : last;
    int s0 = col_src[e],  s1 = col_src[i1], s2 = col_src[i2], s3 = col_src[i3];
    int s4 = col_src[i4], s5 = col_src[i5], s6 = col_src[i6];
    unsigned u0 = t1p[(size_t)s0 * 50 + lane];
    unsigned u1 = (rem > 1) ? t1p[(size_t)s1 * 50 + lane] : 0u;
    unsigned u2 = (rem > 2) ? t1p[(size_t)s2 * 50 + lane] : 0u;
    unsigned u3 = (rem > 3) ? t1p[(size_t)s3 * 50 + lane] : 0u;
    unsigned u4 = (rem > 4) ? t1p[(size_t)s4 * 50 + lane] : 0u;
    unsigned u5 = (rem > 5) ? t1p[(size_t)s5 * 50 + lane] : 0u;
    unsigned u6 = (rem > 6) ? t1p[(size_t)s6 * 50 + lane] : 0u;
    a0 += bf_lo(u0); a1 += bf_hi(u0);
    a0 += bf_lo(u1); a1 += bf_hi(u1);
    a0 += bf_lo(u2); a1 += bf_hi(u2);
    a0 += bf_lo(u3); a1 += bf_hi(u3);
    a0 += bf_lo(u4); a1 += bf_hi(u4);
    a0 += bf_lo(u5); a1 += bf_hi(u5);
    a0 += bf_lo(u6); a1 += bf_hi(u6);
  }
  unsigned su = t1p[(size_t)wid * 50 + lane];
  a0 += bf_lo(su);
  a1 += bf_hi(su);
  float dv = dinv[wid];   // scalar load
  float v0 = fmaxf(dv * a0 + b1[2 * lane], 0.f);
  float v1 = fmaxf(dv * a1 + b1[2 * lane + 1], 0.f);
  h[(size_t)wid * 50 + lane] = pack_bf16(v0, v1);
}

// ------ GEMM2: t2p = bf16( (h @ W2) * dinv )  (N x 100 x 16) ----------------
__global__ __launch_bounds__(256)
void k_gemm2(const unsigned* __restrict__ h, const float* __restrict__ W2,
             const float* __restrict__ dinv, unsigned* __restrict__ t2p, int n) {
  __shared__ alignas(16) float w2s[100][16];
  __shared__ float hs[64][101];
  int tid = threadIdx.x;
  int r0 = blockIdx.x * 64;
  for (int idx = tid; idx < H1 * H2; idx += 256) w2s[idx / 16][idx % 16] = W2[idx];
  for (int idx = tid; idx < 64 * 50; idx += 256) {
    int row = idx / 50, u = idx % 50;
    int gr = r0 + row;
    unsigned v = 0;
    if (gr < n) v = h[(size_t)gr * 50 + u];
    hs[row][2 * u + 0] = bf_lo(v);
    hs[row][2 * u + 1] = bf_hi(v);
  }
  __syncthreads();
  int r = tid & 63, cg = tid >> 6;
  float ax = 0.f, ay = 0.f, az = 0.f, aw = 0.f;
#pragma unroll 4
  for (int k = 0; k < H1; ++k) {
    float a = hs[r][k];
    float4 w = *(const float4*)&w2s[k][cg * 4];
    ax += a * w.x; ay += a * w.y; az += a * w.z; aw += a * w.w;
  }
  int gr = r0 + r;
  if (gr < n) {
    float dv = dinv[gr];
    unsigned u0 = pack_bf16(ax * dv, ay * dv);
    unsigned u1 = pack_bf16(az * dv, aw * dv);
    *(uint2*)(t2p + (size_t)gr * 8 + cg * 2) = make_uint2(u0, u1);
  }
}

// ------- agg2 + bias + relu + row-normalize: embb (N x 16, bf16 packed) -----
__global__ __launch_bounds__(256)
void k_agg2(const unsigned* __restrict__ t2p, const int* __restrict__ row_ptr,
            const int* __restrict__ col_src, const float* __restrict__ dinv,
            const float* __restrict__ b2, unsigned* __restrict__ embb, int n) {
  int wv = __builtin_amdgcn_readfirstlane((int)(threadIdx.x >> 6));  // uniform
  int wid = blockIdx.x * 4 + wv;
  if (wid >= n) return;
  int lane = threadIdx.x & 63;
  int es = lane >> 3, c = lane & 7;
  int beg = row_ptr[wid], end = row_ptr[wid + 1];   // scalar loads
  float a0 = 0.f, a1 = 0.f;
  for (int e = beg + es; e < end; e += 8) {
    int s = col_src[e];
    unsigned u = t2p[(size_t)s * 8 + c];
    a0 += bf_lo(u);
    a1 += bf_hi(u);
  }
  a0 += __shfl_xor(a0, 8, 64);  a1 += __shfl_xor(a1, 8, 64);
  a0 += __shfl_xor(a0, 16, 64); a1 += __shfl_xor(a1, 16, 64);
  a0 += __shfl_xor(a0, 32, 64); a1 += __shfl_xor(a1, 32, 64);
  unsigned su = t2p[(size_t)wid * 8 + c];
  a0 += bf_lo(su);
  a1 += bf_hi(su);
  float dv = dinv[wid];
  float v0 = fmaxf(dv * a0 + b2[2 * c + 0], 0.f);
  float v1 = fmaxf(dv * a1 + b2[2 * c + 1], 0.f);
  float n2 = v0 * v0 + v1 * v1;
  n2 += __shfl_xor(n2, 1, 64);
  n2 += __shfl_xor(n2, 2, 64);
  n2 += __shfl_xor(n2, 4, 64);
  float scale = 1.f / fmaxf(sqrtf(n2), 1.f);
  if (es == 0) {
    embb[(size_t)wid * 8 + c] = pack_bf16(v0 * scale, v1 * scale);  // bf16 table: 3.2MB, L2-fits
  }
}

// ---- scorer B-fragment precompute: one-time, 64 threads ----
__global__ void k_sprep(const float* __restrict__ l1W, uint4* __restrict__ Bt) {
  int lane = threadIdx.x;   // 0..63
  int lr = lane & 15, lg = lane >> 4;
  float wb[16];
#pragma unroll
  for (int i = 0; i < 8; i++) {
    int k0 = lg * 8 + i;
    wb[i] = (lr < 25) ? l1W[k0 * 25 + lr] : 0.f;
    int k1 = 32 + lg * 8 + i;
    wb[8 + i] = (lr < 25 && k1 < 41) ? l1W[k1 * 25 + lr] : 0.f;
  }
  int j1 = 16 + lr;
  float wb2[16];
#pragma unroll
  for (int i = 0; i < 8; i++) {
    int k0 = lg * 8 + i;
    wb2[i] = (j1 < 25) ? l1W[k0 * 25 + j1] : 0.f;
    int k1 = 32 + lg * 8 + i;
    wb2[8 + i] = (j1 < 25 && k1 < 41) ? l1W[k1 * 25 + j1] : 0.f;
  }
  uint4 B00, B01, B10, B11;
  B00.x = pack_bf16(wb[0], wb[1]);  B00.y = pack_bf16(wb[2], wb[3]);
  B00.z = pack_bf16(wb[4], wb[5]);  B00.w = pack_bf16(wb[6], wb[7]);
  B01.x = pack_bf16(wb[8], wb[9]);  B01.y = pack_bf16(wb[10], wb[11]);
  B01.z = pack_bf16(wb[12], wb[13]); B01.w = pack_bf16(wb[14], wb[15]);
  B10.x = pack_bf16(wb2[0], wb2[1]); B10.y = pack_bf16(wb2[2], wb2[3]);
  B10.z = pack_bf16(wb2[4], wb2[5]); B10.w = pack_bf16(wb2[6], wb2[7]);
  B11.x = pack_bf16(wb2[8], wb2[9]); B11.y = pack_bf16(wb2[10], wb2[11]);
  B11.z = pack_bf16(wb2[12], wb2[13]); B11.w = pack_bf16(wb2[14], wb2[15]);
  Bt[lane * 4 + 0] = B00;
  Bt[lane * 4 + 1] = B01;
  Bt[lane * 4 + 2] = B10;
  Bt[lane * 4 + 3] = B11;
}

// ------------ edge scorer v6: Bt-MFMA, 2 tiles/wave, bf16 emb table ---------
// Measured optimum: 1-tile=70us, 2-tile=65us, 4-tile=73us (R14/R16: compiler
// sinks >2 chains' loads; occupancy drops). This is the R13 measured-best.
__global__ __launch_bounds__(256)
void k_score(const unsigned* __restrict__ embb, const int* __restrict__ te,
             const float* __restrict__ PI, const uint4* __restrict__ Bt,
             const float* __restrict__ l1b, const float* __restrict__ lW,
             const float* __restrict__ lb, float* __restrict__ out, int ned) {
  int tid = threadIdx.x;
  int lane = tid & 63, w = tid >> 6;
  int lr = lane & 15, lg = lane >> 4;
  int e0 = blockIdx.x * 128 + w * 32;    // wave: edges [e0, e0+32)
  int ea = e0 + lr, eb = e0 + 16 + lr;
  int eca = (ea < ned) ? ea : 0;
  int ecb = (eb < ned) ? eb : 0;

  uint4 B00 = Bt[lane * 4 + 0];
  uint4 B01 = Bt[lane * 4 + 1];
  uint4 B10 = Bt[lane * 4 + 2];
  uint4 B11 = Bt[lane * 4 + 3];

  const float* pia = PI + (size_t)eca * 25;
  const float* pib = PI + (size_t)ecb * 25;

  uint4 A0a = {0u,0u,0u,0u}, A1a = {0u,0u,0u,0u};
  uint4 A0b = {0u,0u,0u,0u}, A1b = {0u,0u,0u,0u};

  if (lg < 2) {
    int2 uva = *(const int2*)(te + 2 * (size_t)eca);
    int2 uvb = *(const int2*)(te + 2 * (size_t)ecb);
    // one 16B load per (edge,node): 8 bf16 = k slice lg*8..lg*8+7
    uint4 ua = *(const uint4*)(embb + (size_t)uva.x * 8 + lg * 4);
    uint4 va = *(const uint4*)(embb + (size_t)uva.y * 8 + lg * 4);
    uint4 ub = *(const uint4*)(embb + (size_t)uvb.x * 8 + lg * 4);
    uint4 vb = *(const uint4*)(embb + (size_t)uvb.y * 8 + lg * 4);
    A0a.x = sqd_pair(ua.x, va.x); A0a.y = sqd_pair(ua.y, va.y);
    A0a.z = sqd_pair(ua.z, va.z); A0a.w = sqd_pair(ua.w, va.w);
    A0b.x = sqd_pair(ub.x, vb.x); A0b.y = sqd_pair(ub.y, vb.y);
    A0b.z = sqd_pair(ub.z, vb.z); A0b.w = sqd_pair(ub.w, vb.w);
    if (lg == 0) {  // A1: k=32..39 -> PI[16..23]
      f32x4a pa0 = *(const f32x4a*)(pia + 16);
      f32x4a pa1 = *(const f32x4a*)(pia + 20);
      f32x4a pb0 = *(const f32x4a*)(pib + 16);
      f32x4a pb1 = *(const f32x4a*)(pib + 20);
      A1a.x = pack_bf16(pa0[0], pa0[1]); A1a.y = pack_bf16(pa0[2], pa0[3]);
      A1a.z = pack_bf16(pa1[0], pa1[1]); A1a.w = pack_bf16(pa1[2], pa1[3]);
      A1b.x = pack_bf16(pb0[0], pb0[1]); A1b.y = pack_bf16(pb0[2], pb0[3]);
      A1b.z = pack_bf16(pb1[0], pb1[1]); A1b.w = pack_bf16(pb1[2], pb1[3]);
    } else {        // A1: k=40 -> PI[24]
      A1a.x = pack_bf16(pia[24], 0.f);
      A1b.x = pack_bf16(pib[24], 0.f);
    }
  } else {
    const float* ppa = pia + (lg - 2) * 8;   // lg2 -> PI[0..7], lg3 -> PI[8..15]
    const float* ppb = pib + (lg - 2) * 8;
    f32x4a pa0 = *(const f32x4a*)(ppa);
    f32x4a pa1 = *(const f32x4a*)(ppa + 4);
    f32x4a pb0 = *(const f32x4a*)(ppb);
    f32x4a pb1 = *(const f32x4a*)(ppb + 4);
    A0a.x = pack_bf16(pa0[0], pa0[1]); A0a.y = pack_bf16(pa0[2], pa0[3]);
    A0a.z = pack_bf16(pa1[0], pa1[1]); A0a.w = pack_bf16(pa1[2], pa1[3]);
    A0b.x = pack_bf16(pb0[0], pb0[1]); A0b.y = pack_bf16(pb0[2], pb0[3]);
    A0b.z = pack_bf16(pb1[0], pb1[1]); A0b.w = pack_bf16(pb1[2], pb1[3]);
  }

  f32x4 acc0a = {0.f,0.f,0.f,0.f}, acc1a = {0.f,0.f,0.f,0.f};
  f32x4 acc0b = {0.f,0.f,0.f,0.f}, acc1b = {0.f,0.f,0.f,0.f};
  acc0a = __builtin_amdgcn_mfma_f32_16x16x32_bf16(*(bf16x8*)&A0a, *(bf16x8*)&B00, acc0a, 0, 0, 0);
  acc0b = __builtin_amdgcn_mfma_f32_16x16x32_bf16(*(bf16x8*)&A0b, *(bf16x8*)&B00, acc0b, 0, 0, 0);
  acc0a = __builtin_amdgcn_mfma_f32_16x16x32_bf16(*(bf16x8*)&A1a, *(bf16x8*)&B01, acc0a, 0, 0, 0);
  acc0b = __builtin_amdgcn_mfma_f32_16x16x32_bf16(*(bf16x8*)&A1b, *(bf16x8*)&B01, acc0b, 0, 0, 0);
  acc1a = __builtin_amdgcn_mfma_f32_16x16x32_bf16(*(bf16x8*)&A0a, *(bf16x8*)&B10, acc1a, 0, 0, 0);
  acc1b = __builtin_amdgcn_mfma_f32_16x16x32_bf16(*(bf16x8*)&A0b, *(bf16x8*)&B10, acc1b, 0, 0, 0);
  acc1a = __builtin_amdgcn_mfma_f32_16x16x32_bf16(*(bf16x8*)&A1a, *(bf16x8*)&B11, acc1a, 0, 0, 0);
  acc1b = __builtin_amdgcn_mfma_f32_16x16x32_bf16(*(bf16x8*)&A1b, *(bf16x8*)&B11, acc1b, 0, 0, 0);

  // ---- epilogue: leaky-relu + 2nd layer, reduce over j (lr lanes) ----
  int j1 = 16 + lr;
  float bj0 = l1b[lr];
  float wj0 = lW[lr];
  float bj1 = (j1 < 25) ? l1b[j1] : 0.f;
  float wj1 = (j1 < 25) ? lW[j1] : 0.f;
  float lbv = lb[0];

  float pa[4], pb[4];
#pragma unroll
  for (int r = 0; r < 4; r++) {
    float x0 = acc0a[r] + bj0;
    x0 = (x0 > 0.f) ? x0 : 0.2f * x0;
    float x1 = acc1a[r] + bj1;
    x1 = (x1 > 0.f) ? x1 : 0.2f * x1;
    pa[r] = x0 * wj0 + ((j1 < 25) ? x1 * wj1 : 0.f);
    float y0 = acc0b[r] + bj0;
    y0 = (y0 > 0.f) ? y0 : 0.2f * y0;
    float y1 = acc1b[r] + bj1;
    y1 = (y1 > 0.f) ? y1 : 0.2f * y1;
    pb[r] = y0 * wj0 + ((j1 < 25) ? y1 * wj1 : 0.f);
  }
#pragma unroll
  for (int r = 0; r < 4; r++) {
    pa[r] += __shfl_xor(pa[r], 1, 64);
    pb[r] += __shfl_xor(pb[r], 1, 64);
    pa[r] += __shfl_xor(pa[r], 2, 64);
    pb[r] += __shfl_xor(pb[r], 2, 64);
    pa[r] += __shfl_xor(pa[r], 4, 64);
    pb[r] += __shfl_xor(pb[r], 4, 64);
    pa[r] += __shfl_xor(pa[r], 8, 64);
    pb[r] += __shfl_xor(pb[r], 8, 64);
  }
  if (lr == 0) {
#pragma unroll
    for (int r = 0; r < 4; r++) {
      int eoa = e0 + lg * 4 + r;
      if (eoa < ned) {
        float s = fminf(fabsf(pa[r] + lbv), 40.f);
        out[eoa] = 1.f / (1.f + __expf(-(2.f - s)));
      }
      int eob = e0 + 16 + lg * 4 + r;
      if (eob < ned) {
        float s = fminf(fabsf(pb[r] + lbv), 40.f);
        out[eob] = 1.f / (1.f + __expf(-(2.f - s)));
      }
    }
  }
}

// ---------------- launch -----------------------------------------------------
extern "C" void kernel_launch(void* const* d_in, const int* in_sizes, int n_in,
                              void* d_out, int out_size, void* d_ws, size_t ws_size,
                              hipStream_t stream) {
  const float* x   = (const float*)d_in[0];
  const int*   ei  = (const int*)d_in[1];
  const int*   te  = (const int*)d_in[2];
  const float* PI  = (const float*)d_in[3];
  const float* W1  = (const float*)d_in[4];
  const float* b1  = (const float*)d_in[5];
  const float* W2  = (const float*)d_in[6];
  const float* b2  = (const float*)d_in[7];
  const float* l1W = (const float*)d_in[8];
  const float* l1b = (const float*)d_in[9];
  const float* lW  = (const float*)d_in[10];
  const float* lb  = (const float*)d_in[11];
  float* out = (float*)d_out;

  int h1 = in_sizes[5];            // 100
  int F  = in_sizes[4] / h1;       // 256
  int N  = in_sizes[0] / F;        // 100000
  int E  = in_sizes[1] / 2;        // 1600000
  int ED = in_sizes[2] / 2;        // 1000000

  const int* src  = ei;
  const int* dstp = ei + E;

  int shift = 8;
  while ((((size_t)N + ((size_t)1 << shift) - 1) >> shift) > 512) shift++;
  int nbuc = (N + (1 << shift) - 1) >> shift;

  size_t off = 0;
  auto alloc = [&](size_t bytes) -> void* {
    void* p = (char*)d_ws + off;
    off += (bytes + 255) & ~(size_t)255;
    return p;
  };
  float*          dinv     = (float*)alloc((size_t)N * 4);
  int*            row_ptr  = (int*)alloc((size_t)(N + 1) * 4);
  int*            bcnt     = (int*)alloc(512 * 4);
  int*            bbase    = (int*)alloc(520 * 4);
  int*            bfill    = (int*)alloc(512 * 4);
  int*            col_src  = (int*)alloc((size_t)E * 4);
  unsigned short* W1bf     = (unsigned short*)alloc((size_t)NPAD * FDIM * 2);
  uint4*          Bt       = (uint4*)alloc(64 * 4 * 16);
  unsigned*       t1p      = (unsigned*)alloc((size_t)N * 50 * 4 + 256);
  unsigned*       h        = (unsigned*)alloc((size_t)N * 50 * 4);
  unsigned*       t2p      = (unsigned*)alloc((size_t)N * 8 * 4);
  unsigned*       embb     = (unsigned*)alloc((size_t)N * 8 * 4);   // bf16 packed

  int2* tpair = (int2*)h;          // temp binned edges alias h (dead until agg1)

  int nwb = (E + BINCH - 1) / BINCH;

  hipMemsetAsync(bcnt, 0, 512 * 4, stream);
  k_bincnt<<<nwb, 256, 0, stream>>>(dstp, bcnt, E, shift);
  k_bscan<<<1, 512, 0, stream>>>(bcnt, bbase, bfill, nbuc, E);
  k_binwrite<<<nwb, 256, 0, stream>>>(src, dstp, bfill, tpair, E, shift);
  k_deg2s<<<nbuc, 256, 0, stream>>>(tpair, bbase, dinv, row_ptr, N, E, shift);
  k_csr2<<<nbuc, 256, 0, stream>>>(tpair, bbase, row_ptr, col_src, N, shift);
  k_w1cast<<<(NPAD * FDIM + 255) / 256, 256, 0, stream>>>(W1, W1bf);
  k_sprep<<<1, 64, 0, stream>>>(l1W, Bt);
  k_gemm1m<<<(N + 127) / 128, 512, 0, stream>>>(x, W1bf, dinv, (unsigned short*)t1p, N);
  k_agg1<<<(int)(((size_t)N * 64 + 255) / 256), 256, 0, stream>>>(t1p, row_ptr, col_src, dinv, b1, h, N);
  k_gemm2<<<(N + 63) / 64, 256, 0, stream>>>(h, W2, dinv, t2p, N);
  k_agg2<<<(int)(((size_t)N * 64 + 255) / 256), 256, 0, stream>>>(t2p, row_ptr, col_src, dinv, b2, embb, N);
  k_score<<<(ED + 127) / 128, 256, 0, stream>>>(embb, te, PI, Bt, l1b, lW, lb, out, ED);
}